// Round 7
// baseline (1068.332 us; speedup 1.0000x reference)
//
#include <hip/hip_runtime.h>
#include <hip/hip_fp16.h>
#include <cstdint>

#define FIN 512
#define HID 16
#define NCLS 40
#define SHIFT 8          // 256 nodes per coarse bucket
#define NBCAP 512        // LDS capacity for bucket histograms (nb = 391 for N=100000)
#define NBLK 512         // blocks for fused scatter
#define BR 64            // rows per block in linear1
#define KC 32            // K-chunk in linear1
#define CAP 12288        // padded slots per bucket (mean 8184, sigma ~90 -> 45 sigma)

// Clang vector types for __builtin_nontemporal_load (HIP_vector_type is a class -> rejected)
typedef int   iv4 __attribute__((ext_vector_type(4)));
typedef float fv4 __attribute__((ext_vector_type(4)));

// Memory-policy rules learned on this problem (gfx950):
// R1: scattered global atomics (3.2M over 100K addrs) ~25 G/s, 32x write amp. Never O(E).
// R4: NT stores are write-around -- scattered 1B/4B NT stores bypass L2 write-combining
//     (217 MB HBM writes vs ~17 MB plain). NT stores ONLY for full-line contiguous streams.
// R5: NT loads bypass L1 -- on streams with lane-duplicated addresses or multi-touch
//     lines they multiply L2 traffic (+28 us). NT loads only single-touch coalesced.
// R7: aggs consume bucket-ordered tmp_tgt directly with per-bucket LDS fp32 accumulators
//     (ds_add_f32) -- no CSR (edges/row_ptr) needed at all.

// ---------------- zero bucket cursors ----------------

__global__ void zerocur_kernel(int* __restrict__ gcur) {
    int t = threadIdx.x;                 // 512 threads
    gcur[t] = 0;
    gcur[NBCAP + t] = 0;
}

// ---------------- fused count+scatter: contiguous chunk, 2 passes, range reservation --
// Pass A: LDS histogram of this block's chunk (both src and tgt buckets).
// Reserve: one global atomicAdd per (block,bucket) -> disjoint ranges in padded buckets.
// Pass B: re-read chunk (L2-resident, ~50 KB/block) and scatter via LDS cursors.
// tmp_src[pos] = low 8 bits of src (bucket implied by position)
// tmp_tgt[pos] = (tgt&255)<<17 | src   (src < 2^17)

__global__ void fused_scatter_kernel(const int* __restrict__ ei, int E, int nb,
                                     int* __restrict__ gcur,          // [NBCAP] src, [NBCAP] tgt
                                     unsigned char* __restrict__ tmp_src,
                                     unsigned int* __restrict__ tmp_tgt) {
    __shared__ int hs[NBCAP], ht[NBCAP];
    int t = threadIdx.x;
    for (int j = t; j < NBCAP; j += 256) { hs[j] = 0; ht[j] = 0; }
    __syncthreads();
    if ((E & 3) == 0) {
        const iv4* s4 = (const iv4*)ei;
        const iv4* t4 = (const iv4*)(ei + E);
        int E4 = E >> 2;
        int per = (E4 + NBLK - 1) / NBLK;
        int lo = blockIdx.x * per;
        int hi = lo + per; if (hi > E4) hi = E4;
        for (int i = lo + t; i < hi; i += 256) {
            iv4 s = s4[i];
            iv4 tt = t4[i];
            atomicAdd(&hs[s.x >> SHIFT], 1); atomicAdd(&hs[s.y >> SHIFT], 1);
            atomicAdd(&hs[s.z >> SHIFT], 1); atomicAdd(&hs[s.w >> SHIFT], 1);
            atomicAdd(&ht[tt.x >> SHIFT], 1); atomicAdd(&ht[tt.y >> SHIFT], 1);
            atomicAdd(&ht[tt.z >> SHIFT], 1); atomicAdd(&ht[tt.w >> SHIFT], 1);
        }
        __syncthreads();
        for (int j = t; j < nb; j += 256) {
            int v = hs[j];
            int base = atomicAdd(&gcur[j], v);
            hs[j] = j * CAP + base;
            int w = ht[j];
            int baset = atomicAdd(&gcur[NBCAP + j], w);
            ht[j] = j * CAP + baset;
        }
        __syncthreads();
        // pass B: scatter (chunk is L2-hot); PLAIN stores -> L2 write-combining (R4!)
        for (int i = lo + t; i < hi; i += 256) {
            iv4 s = s4[i];
            iv4 tt = t4[i];
            int p;
            p = atomicAdd(&hs[s.x >> SHIFT], 1); tmp_src[p] = (unsigned char)(s.x & 255);
            p = atomicAdd(&hs[s.y >> SHIFT], 1); tmp_src[p] = (unsigned char)(s.y & 255);
            p = atomicAdd(&hs[s.z >> SHIFT], 1); tmp_src[p] = (unsigned char)(s.z & 255);
            p = atomicAdd(&hs[s.w >> SHIFT], 1); tmp_src[p] = (unsigned char)(s.w & 255);
            p = atomicAdd(&ht[tt.x >> SHIFT], 1); tmp_tgt[p] = ((unsigned int)(tt.x & 255) << 17) | (unsigned int)s.x;
            p = atomicAdd(&ht[tt.y >> SHIFT], 1); tmp_tgt[p] = ((unsigned int)(tt.y & 255) << 17) | (unsigned int)s.y;
            p = atomicAdd(&ht[tt.z >> SHIFT], 1); tmp_tgt[p] = ((unsigned int)(tt.z & 255) << 17) | (unsigned int)s.z;
            p = atomicAdd(&ht[tt.w >> SHIFT], 1); tmp_tgt[p] = ((unsigned int)(tt.w & 255) << 17) | (unsigned int)s.w;
        }
    } else {
        int per = (E + NBLK - 1) / NBLK;
        int lo = blockIdx.x * per;
        int hi = lo + per; if (hi > E) hi = E;
        for (int i = lo + t; i < hi; i += 256) {
            atomicAdd(&hs[ei[i] >> SHIFT], 1);
            atomicAdd(&ht[ei[E + i] >> SHIFT], 1);
        }
        __syncthreads();
        for (int j = t; j < nb; j += 256) {
            int v = hs[j];
            int base = atomicAdd(&gcur[j], v);
            hs[j] = j * CAP + base;
            int w = ht[j];
            int baset = atomicAdd(&gcur[NBCAP + j], w);
            ht[j] = j * CAP + baset;
        }
        __syncthreads();
        for (int i = lo + t; i < hi; i += 256) {
            int s = ei[i], tg = ei[E + i];
            int ps = atomicAdd(&hs[s >> SHIFT], 1);
            tmp_src[ps] = (unsigned char)(s & 255);
            int pt = atomicAdd(&ht[tg >> SHIFT], 1);
            tmp_tgt[pt] = ((unsigned int)(tg & 255) << 17) | (unsigned int)s;
        }
    }
}

// ---------------- dinv: per-bucket src-degree histogram (was fine phase 1) ----------

__global__ void dinv_kernel(const unsigned char* __restrict__ tmp_src,
                            const int* __restrict__ gcur,
                            float* __restrict__ dinv, int N) {
    __shared__ int hist[256];
    int b = blockIdx.x, t = threadIdx.x;
    hist[t] = 0;
    __syncthreads();
    int scnt = gcur[b];
    const unsigned int* sp = (const unsigned int*)(tmp_src + (size_t)b * CAP);  // CAP%4==0
    int s4n = scnt >> 2;
    for (int i = t; i < s4n; i += 256) {
        unsigned int w = sp[i];
        atomicAdd(&hist[w & 255], 1);
        atomicAdd(&hist[(w >> 8) & 255], 1);
        atomicAdd(&hist[(w >> 16) & 255], 1);
        atomicAdd(&hist[w >> 24], 1);
    }
    for (int i = (s4n << 2) + t; i < scnt; i += 256)
        atomicAdd(&hist[tmp_src[(size_t)b * CAP + i]], 1);
    __syncthreads();
    int node = b * 256 + t;
    if (node < N) dinv[node] = rsqrtf((float)(hist[t] + 1));   // +1 self loop
}

// ---------------- linear layer 1: h1s = fp16( dinv[r] * (X @ W1 + b1) ) ----------------
// Pre-scaling by dinv[src] makes aggregation messages pure adds (norm = dinv_s*dinv_t).
// NT load on x is correct: single-touch, fully-coalesced, never re-read (R5 rule).

__global__ __launch_bounds__(256, 4)
void linear1_kernel(const float* __restrict__ x, const float* __restrict__ w1,
                    const float* __restrict__ b1, const float* __restrict__ dinv,
                    __half* __restrict__ h1h, int n) {
    __shared__ float xs[KC][BR + 2];   // [32][66] = 8.4 KB
    __shared__ float wsc[KC * HID];    // 2 KB
    __shared__ float bl[HID];
    int t = threadIdx.x;
    if (t < HID) bl[t] = b1[t];
    int row0 = blockIdx.x * BR;
    int rp = t >> 2;            // 0..63 -> row
    int cq = (t & 3) * 4;       // channel quad
    float acc[4] = {0, 0, 0, 0};

    fv4 xp[2];
    float wp[2];
    int rr_[2], kk_[2];
#pragma unroll
    for (int u = 0; u < 2; ++u) {
        int i = t + u * 256;
        rr_[u] = i >> 3;            // row in tile (0..63)
        kk_[u] = (i & 7) * 4;       // k within chunk
    }
    auto prefetch = [&](int kc) {
#pragma unroll
        for (int u = 0; u < 2; ++u) {
            int grow = row0 + rr_[u];
            if (grow < n) {
                xp[u] = __builtin_nontemporal_load((const fv4*)(x + (size_t)grow * FIN + kc + kk_[u]));
            } else {
                xp[u] = (fv4){0.f, 0.f, 0.f, 0.f};
            }
        }
        wp[0] = w1[kc * HID + t];
        wp[1] = w1[kc * HID + t + 256];
    };

    prefetch(0);
    for (int kc = 0; kc < FIN; kc += KC) {
        __syncthreads();
#pragma unroll
        for (int u = 0; u < 2; ++u) {
            xs[kk_[u] + 0][rr_[u]] = xp[u].x;
            xs[kk_[u] + 1][rr_[u]] = xp[u].y;
            xs[kk_[u] + 2][rr_[u]] = xp[u].z;
            xs[kk_[u] + 3][rr_[u]] = xp[u].w;
        }
        wsc[t] = wp[0];
        wsc[t + 256] = wp[1];
        __syncthreads();
        if (kc + KC < FIN) prefetch(kc + KC);
#pragma unroll 8
        for (int k = 0; k < KC; ++k) {
            float xv = xs[k][rp];
            float4 wv = *(const float4*)&wsc[k * HID + cq];
            acc[0] = fmaf(xv, wv.x, acc[0]);
            acc[1] = fmaf(xv, wv.y, acc[1]);
            acc[2] = fmaf(xv, wv.z, acc[2]);
            acc[3] = fmaf(xv, wv.w, acc[3]);
        }
    }
    int r0 = row0 + rp;
    if (r0 < n) {
        float dv = dinv[r0];
        __half2* hp = (__half2*)(h1h + (size_t)r0 * HID + cq);
        hp[0] = __floats2half2_rn(dv * (acc[0] + bl[cq + 0]), dv * (acc[1] + bl[cq + 1]));
        hp[1] = __floats2half2_rn(dv * (acc[2] + bl[cq + 2]), dv * (acc[3] + bl[cq + 3]));
    }
}

// ---------------- agg1: bucket-parallel LDS fp32 accumulation from tmp_tgt ----------
// acc[tl][c] += h1s[src][c]  (pure adds; features pre-scaled by dinv[src])
// acc[tl][16] += dinv[src]   (for rowsum)
// Epilogue: gh[t] = relu(dinv_t^2*(self + acc)), rowsum = dv*(dv + accd).

__global__ __launch_bounds__(1024, 4)
void agg1_kernel(const __half* __restrict__ in,
                 const unsigned int* __restrict__ tmp_tgt,
                 const int* __restrict__ gcur,
                 const float* __restrict__ dinv,
                 __half* __restrict__ gh, float* __restrict__ rowsum, int n) {
    __shared__ float acc[256 * 17];     // stride 17 (odd) -> bank-spread; 17.4 KB
    int b = blockIdx.x;
    int t = threadIdx.x;
    for (int j = t; j < 256 * 17; j += 1024) acc[j] = 0.f;
    __syncthreads();
    int cnt = gcur[NBCAP + b];
    size_t base = (size_t)b * CAP;
    int slot = t >> 3;                  // 0..127
    int c2 = t & 7;
    const __half2* tab = (const __half2*)in;
    for (int i = slot; i < cnt; i += 128) {
        unsigned int w = tmp_tgt[base + i];     // 8 lanes same addr; 8 slots/wave = 32B seg
        int tl = (int)(w >> 17);
        int src = (int)(w & 0x1FFFF);
        float2 v = __half22float2(tab[(size_t)src * 8 + c2]);
        atomicAdd(&acc[tl * 17 + 2 * c2], v.x);
        atomicAdd(&acc[tl * 17 + 2 * c2 + 1], v.y);
        if (c2 == 0) atomicAdd(&acc[tl * 17 + 16], dinv[src]);
    }
    __syncthreads();
    int node = b * 256 + t;
    if (t < 256 && node < n) {
        float dv = dinv[node];
        float dv2 = dv * dv;
        const __half2* hp = tab + (size_t)node * 8;
        __half2* gp = (__half2*)gh + (size_t)node * 8;
#pragma unroll
        for (int c = 0; c < 8; ++c) {
            float2 sv = __half22float2(hp[c]);
            float a0 = fmaxf(dv2 * (sv.x + acc[t * 17 + 2 * c]), 0.f);
            float a1 = fmaxf(dv2 * (sv.y + acc[t * 17 + 2 * c + 1]), 0.f);
            gp[c] = __floats2half2_rn(a0, a1);
        }
        rowsum[node] = dv * (dv + acc[t * 17 + 16]);
    }
}

// ---------------- agg2 + final fused: bucket-parallel accumulate + linear + softmax ---

__global__ __launch_bounds__(1024, 4)
void agg2_kernel(const __half* __restrict__ in,        // gh
                 const unsigned int* __restrict__ tmp_tgt,
                 const int* __restrict__ gcur,
                 const float* __restrict__ dinv,
                 const float* __restrict__ rowsum,
                 const float* __restrict__ w2, const float* __restrict__ b2,
                 float* __restrict__ out, int n) {
    __shared__ float acc[256 * 17];     // 16 used; stride 17 for banks
    __shared__ float wl[HID * NCLS];
    __shared__ float bl[NCLS];
    int t = threadIdx.x;
    for (int i = t; i < HID * NCLS; i += 1024) wl[i] = w2[i];
    if (t < NCLS) bl[t] = b2[t];
    for (int j = t; j < 256 * 17; j += 1024) acc[j] = 0.f;
    __syncthreads();
    int b = blockIdx.x;
    int cnt = gcur[NBCAP + b];
    size_t base = (size_t)b * CAP;
    int slot = t >> 3, c2 = t & 7;
    const __half2* tab = (const __half2*)in;
    for (int i = slot; i < cnt; i += 128) {
        unsigned int w = tmp_tgt[base + i];
        int tl = (int)(w >> 17);
        int src = (int)(w & 0x1FFFF);
        float2 v = __half22float2(tab[(size_t)src * 8 + c2]);
        atomicAdd(&acc[tl * 17 + 2 * c2], v.x);
        atomicAdd(&acc[tl * 17 + 2 * c2 + 1], v.y);
    }
    __syncthreads();
    if (t < 512) {
        int nl2 = t >> 1, half = t & 1;      // pair (2k,2k+1) shares node -> shfl_xor(1) safe
        int node = b * 256 + nl2;
        if (node < n) {
            float dv = dinv[node];
            const __half2* hp = tab + (size_t)node * 8;
            float h[HID];
#pragma unroll
            for (int c = 0; c < 8; ++c) {
                float2 sv = __half22float2(hp[c]);
                h[2 * c]     = dv * (sv.x + acc[nl2 * 17 + 2 * c]);
                h[2 * c + 1] = dv * (sv.y + acc[nl2 * 17 + 2 * c + 1]);
            }
            float rs = rowsum[node];
            int c0 = half * 20;
            float z[20];
#pragma unroll
            for (int c = 0; c < 20; ++c) {
                float s = rs * bl[c0 + c];
#pragma unroll
                for (int j = 0; j < HID; ++j) s = fmaf(h[j], wl[j * NCLS + c0 + c], s);
                z[c] = s;
            }
            float m = z[0];
#pragma unroll
            for (int c = 1; c < 20; ++c) m = fmaxf(m, z[c]);
            m = fmaxf(m, __shfl_xor(m, 1));
            float se = 0.f;
#pragma unroll
            for (int c = 0; c < 20; ++c) se += __expf(z[c] - m);
            se += __shfl_xor(se, 1);
            float lse = m + __logf(se);
            float* orow = out + (size_t)node * NCLS + c0;
#pragma unroll
            for (int c = 0; c < 20; ++c) orow[c] = z[c] - lse;
        }
    }
}

// ---------------- launch ----------------

extern "C" void kernel_launch(void* const* d_in, const int* in_sizes, int n_in,
                              void* d_out, int out_size, void* d_ws, size_t ws_size,
                              hipStream_t stream) {
    const float* x  = (const float*)d_in[0];
    const int*   ei = (const int*)d_in[1];
    const float* w1 = (const float*)d_in[2];
    const float* b1 = (const float*)d_in[3];
    const float* w2 = (const float*)d_in[4];
    const float* b2 = (const float*)d_in[5];
    float* out = (float*)d_out;

    int N = in_sizes[0] / FIN;     // 100000
    int E = in_sizes[1] / 2;       // 3200000
    int nb = (N + 255) >> SHIFT;   // 391 coarse buckets (<= NBCAP)

    char* p = (char*)d_ws;
    auto alloc = [&](size_t bytes) -> char* {
        char* r = p;
        p += (bytes + 255) / 256 * 256;
        return r;
    };
    int*   gcur      = (int*)alloc((size_t)2 * NBCAP * 4);
    float* dinv      = (float*)alloc((size_t)N * 4);
    unsigned char* tmp_src = (unsigned char*)alloc((size_t)nb * CAP);      // 4.8 MB
    unsigned int*  tmp_tgt = (unsigned int*)alloc((size_t)nb * CAP * 4);   // 19.2 MB
    __half* h1h      = (__half*)alloc((size_t)N * HID * 2);                // 3.2 MB
    __half* gh       = (__half*)alloc((size_t)N * HID * 2);                // 3.2 MB
    float*  rowsum   = (float*)alloc((size_t)N * 4);

    zerocur_kernel<<<1, NBCAP, 0, stream>>>(gcur);
    fused_scatter_kernel<<<NBLK, 256, 0, stream>>>(ei, E, nb, gcur, tmp_src, tmp_tgt);
    dinv_kernel<<<nb, 256, 0, stream>>>(tmp_src, gcur, dinv, N);
    linear1_kernel<<<(N + BR - 1) / BR, 256, 0, stream>>>(x, w1, b1, dinv, h1h, N);
    agg1_kernel<<<nb, 1024, 0, stream>>>(h1h, tmp_tgt, gcur, dinv, gh, rowsum, N);
    agg2_kernel<<<nb, 1024, 0, stream>>>(gh, tmp_tgt, gcur, dinv, rowsum, w2, b2, out, N);
}

// Round 8
// 472.379 us; speedup vs baseline: 2.2616x; 2.2616x over previous
//
#include <hip/hip_runtime.h>
#include <hip/hip_fp16.h>
#include <cstdint>

#define FIN 512
#define HID 16
#define NCLS 40
#define SHIFT 8          // 256 nodes per coarse bucket
#define NBCAP 512        // LDS capacity for bucket histograms (nb = 391 for N=100000)
#define NBLK 512         // blocks for fused scatter
#define BR 64            // rows per block in linear1
#define KC 32            // K-chunk in linear1
#define CAP 12288        // padded slots per bucket (mean 8184, sigma ~90 -> 45 sigma)
#define FCAP 12288       // fine-kernel LDS staging capacity (48 KB)

// Clang vector types for __builtin_nontemporal_load (HIP_vector_type is a class -> rejected)
typedef int   iv4 __attribute__((ext_vector_type(4)));
typedef float fv4 __attribute__((ext_vector_type(4)));
typedef unsigned int uv4 __attribute__((ext_vector_type(4)));

// Memory-policy rules learned on this problem (gfx950):
// R1: scattered global atomics (3.2M over 100K addrs) ~25 G/s, 32x write amp. Never O(E).
// R4: NT stores are write-around -- scattered 1B/4B NT stores bypass L2 write-combining
//     (217 MB HBM writes vs ~17 MB plain). NT stores ONLY for full-line contiguous streams.
// R5: NT loads bypass L1 -- on streams with lane-duplicated addresses or multi-touch
//     lines they multiply L2 traffic (+28 us). NT loads only single-touch coalesced.
// R7: fp32 atomicAdd (LDS or global) lowers to CAS loops -> ~0.06 ops/cyc/CU. NEVER
//     at per-edge rate. Register accumulation + shuffle reduction only.

// ---------------- zero bucket cursors ----------------

__global__ void zerocur_kernel(int* __restrict__ gcur) {
    int t = threadIdx.x;                 // 512 threads
    gcur[t] = 0;
    gcur[NBCAP + t] = 0;
}

// ---------------- fused count+scatter: contiguous chunk, 2 passes, range reservation --
// Pass A: LDS histogram of this block's chunk (both src and tgt buckets).
// Reserve: one global atomicAdd per (block,bucket) -> disjoint ranges in padded buckets.
// Pass B: re-read chunk (L2-resident, ~50 KB/block) and scatter via LDS cursors.
// tmp_src[pos] = low 8 bits of src (bucket implied by position)
// tmp_tgt[pos] = (tgt&255)<<17 | src   (src < 2^17)

__global__ void fused_scatter_kernel(const int* __restrict__ ei, int E, int nb,
                                     int* __restrict__ gcur,          // [NBCAP] src, [NBCAP] tgt
                                     unsigned char* __restrict__ tmp_src,
                                     unsigned int* __restrict__ tmp_tgt) {
    __shared__ int hs[NBCAP], ht[NBCAP];
    int t = threadIdx.x;
    for (int j = t; j < NBCAP; j += 256) { hs[j] = 0; ht[j] = 0; }
    __syncthreads();
    if ((E & 3) == 0) {
        const iv4* s4 = (const iv4*)ei;
        const iv4* t4 = (const iv4*)(ei + E);
        int E4 = E >> 2;
        int per = (E4 + NBLK - 1) / NBLK;
        int lo = blockIdx.x * per;
        int hi = lo + per; if (hi > E4) hi = E4;
        for (int i = lo + t; i < hi; i += 256) {
            iv4 s = s4[i];
            iv4 tt = t4[i];
            atomicAdd(&hs[s.x >> SHIFT], 1); atomicAdd(&hs[s.y >> SHIFT], 1);
            atomicAdd(&hs[s.z >> SHIFT], 1); atomicAdd(&hs[s.w >> SHIFT], 1);
            atomicAdd(&ht[tt.x >> SHIFT], 1); atomicAdd(&ht[tt.y >> SHIFT], 1);
            atomicAdd(&ht[tt.z >> SHIFT], 1); atomicAdd(&ht[tt.w >> SHIFT], 1);
        }
        __syncthreads();
        for (int j = t; j < nb; j += 256) {
            int v = hs[j];
            int base = atomicAdd(&gcur[j], v);
            hs[j] = j * CAP + base;
            int w = ht[j];
            int baset = atomicAdd(&gcur[NBCAP + j], w);
            ht[j] = j * CAP + baset;
        }
        __syncthreads();
        // pass B: scatter (chunk is L2-hot); PLAIN stores -> L2 write-combining (R4!)
        for (int i = lo + t; i < hi; i += 256) {
            iv4 s = s4[i];
            iv4 tt = t4[i];
            int p;
            p = atomicAdd(&hs[s.x >> SHIFT], 1); tmp_src[p] = (unsigned char)(s.x & 255);
            p = atomicAdd(&hs[s.y >> SHIFT], 1); tmp_src[p] = (unsigned char)(s.y & 255);
            p = atomicAdd(&hs[s.z >> SHIFT], 1); tmp_src[p] = (unsigned char)(s.z & 255);
            p = atomicAdd(&hs[s.w >> SHIFT], 1); tmp_src[p] = (unsigned char)(s.w & 255);
            p = atomicAdd(&ht[tt.x >> SHIFT], 1); tmp_tgt[p] = ((unsigned int)(tt.x & 255) << 17) | (unsigned int)s.x;
            p = atomicAdd(&ht[tt.y >> SHIFT], 1); tmp_tgt[p] = ((unsigned int)(tt.y & 255) << 17) | (unsigned int)s.y;
            p = atomicAdd(&ht[tt.z >> SHIFT], 1); tmp_tgt[p] = ((unsigned int)(tt.z & 255) << 17) | (unsigned int)s.z;
            p = atomicAdd(&ht[tt.w >> SHIFT], 1); tmp_tgt[p] = ((unsigned int)(tt.w & 255) << 17) | (unsigned int)s.w;
        }
    } else {
        int per = (E + NBLK - 1) / NBLK;
        int lo = blockIdx.x * per;
        int hi = lo + per; if (hi > E) hi = E;
        for (int i = lo + t; i < hi; i += 256) {
            atomicAdd(&hs[ei[i] >> SHIFT], 1);
            atomicAdd(&ht[ei[E + i] >> SHIFT], 1);
        }
        __syncthreads();
        for (int j = t; j < nb; j += 256) {
            int v = hs[j];
            int base = atomicAdd(&gcur[j], v);
            hs[j] = j * CAP + base;
            int w = ht[j];
            int baset = atomicAdd(&gcur[NBCAP + j], w);
            ht[j] = j * CAP + baset;
        }
        __syncthreads();
        for (int i = lo + t; i < hi; i += 256) {
            int s = ei[i], tg = ei[E + i];
            int ps = atomicAdd(&hs[s >> SHIFT], 1);
            tmp_src[ps] = (unsigned char)(s & 255);
            int pt = atomicAdd(&ht[tg >> SHIFT], 1);
            tmp_tgt[pt] = ((unsigned int)(tg & 255) << 17) | (unsigned int)s;
        }
    }
}

// ---------------- fine (merged): per-bucket prefix + deg->dinv AND CSR build ----------
// bucketscan folded in: each block computes beg = sum of tgt counts of buckets < b.
// Plain loads (R5). uint4/uint vectorized stream reads. INT LDS atomics only (R7).

__global__ void fine_kernel(const unsigned char* __restrict__ tmp_src,
                            const unsigned int* __restrict__ tmp_tgt,
                            const int* __restrict__ gcur,
                            float* __restrict__ dinv, int* __restrict__ row_ptr,
                            int* __restrict__ edges, int N, int E, int nb) {
    __shared__ unsigned int stage[FCAP];   // 48 KB
    __shared__ int hist[256];
    __shared__ int h2[256];
    __shared__ int scan[256];
    int b = blockIdx.x;
    int t = threadIdx.x;
    int scnt = gcur[b];
    int cnt  = gcur[NBCAP + b];
    int sb0 = b * CAP;
    // prefix over tgt bucket totals (gcur is L2-hot, broadcast across blocks)
    int part = 0;
    for (int j = t; j < b; j += 256) part += gcur[NBCAP + j];
    scan[t] = part;
    __syncthreads();
    for (int off = 128; off > 0; off >>= 1) {
        if (t < off) scan[t] += scan[t + off];
        __syncthreads();
    }
    int beg = scan[0];
    __syncthreads();
    bool staged = (cnt <= FCAP);
    hist[t] = 0;
    h2[t] = 0;
    __syncthreads();
    // overlap: stage tgt slice into LDS (uint4) while histogramming src degrees (uint)
    if (staged) {
        const uv4* tp = (const uv4*)(tmp_tgt + sb0);   // sb0*4 bytes, 16B-aligned
        int c4 = cnt >> 2;
        for (int i = t; i < c4; i += 256) {
            uv4 w = tp[i];
            ((uv4*)stage)[i] = w;
        }
        for (int i = (c4 << 2) + t; i < cnt; i += 256) stage[i] = tmp_tgt[sb0 + i];
    }
    {
        const unsigned int* sp = (const unsigned int*)(tmp_src + sb0);  // 4B-aligned
        int s4n = scnt >> 2;
        for (int i = t; i < s4n; i += 256) {
            unsigned int w = sp[i];
            atomicAdd(&hist[w & 255], 1);
            atomicAdd(&hist[(w >> 8) & 255], 1);
            atomicAdd(&hist[(w >> 16) & 255], 1);
            atomicAdd(&hist[w >> 24], 1);
        }
        for (int i = (s4n << 2) + t; i < scnt; i += 256)
            atomicAdd(&hist[tmp_src[sb0 + i]], 1);
    }
    __syncthreads();
    int node = b * 256 + t;
    if (node < N) dinv[node] = rsqrtf((float)(hist[t] + 1));   // +1 self loop
    // phase 2: tgt histogram -> row_ptr -> edge scatter
    if (staged) {
        for (int i = t; i < cnt; i += 256) atomicAdd(&h2[stage[i] >> 17], 1);
    } else {
        for (int i = t; i < cnt; i += 256) atomicAdd(&h2[tmp_tgt[sb0 + i] >> 17], 1);
    }
    __syncthreads();
    int v = h2[t];
    scan[t] = v;
    __syncthreads();
    for (int off = 1; off < 256; off <<= 1) {
        int a = (t >= off) ? scan[t - off] : 0;
        __syncthreads();
        scan[t] += a;
        __syncthreads();
    }
    int ex = scan[t] - v;       // exclusive offset within bucket
    if (node < N) row_ptr[node] = beg + ex;
    if (b == nb - 1 && t == 0) row_ptr[N] = E;
    h2[t] = ex;                 // reuse as cursor
    __syncthreads();
    if (staged) {
        for (int i = t; i < cnt; i += 256) {
            unsigned int w = stage[i];
            int tl = (int)(w >> 17);
            edges[beg + atomicAdd(&h2[tl], 1)] = (int)(w & 0x1FFFF);
        }
    } else {
        for (int i = t; i < cnt; i += 256) {
            unsigned int w = tmp_tgt[sb0 + i];
            int tl = (int)(w >> 17);
            edges[beg + atomicAdd(&h2[tl], 1)] = (int)(w & 0x1FFFF);
        }
    }
}

// ---------------- linear layer 1: h1s = fp16( dinv[r] * (X @ W1 + b1) ) ----------------
// Pre-scaling by dinv[src] makes aggregation messages pure adds (norm = dinv_s*dinv_t).
// NT load on x is correct: single-touch, fully-coalesced, never re-read (R5 rule).

__global__ __launch_bounds__(256, 4)
void linear1_kernel(const float* __restrict__ x, const float* __restrict__ w1,
                    const float* __restrict__ b1, const float* __restrict__ dinv,
                    __half* __restrict__ h1h, int n) {
    __shared__ float xs[KC][BR + 2];   // [32][66] = 8.4 KB
    __shared__ float wsc[KC * HID];    // 2 KB
    __shared__ float bl[HID];
    int t = threadIdx.x;
    if (t < HID) bl[t] = b1[t];
    int row0 = blockIdx.x * BR;
    int rp = t >> 2;            // 0..63 -> row
    int cq = (t & 3) * 4;       // channel quad
    float acc[4] = {0, 0, 0, 0};

    fv4 xp[2];
    float wp[2];
    int rr_[2], kk_[2];
#pragma unroll
    for (int u = 0; u < 2; ++u) {
        int i = t + u * 256;
        rr_[u] = i >> 3;            // row in tile (0..63)
        kk_[u] = (i & 7) * 4;       // k within chunk
    }
    auto prefetch = [&](int kc) {
#pragma unroll
        for (int u = 0; u < 2; ++u) {
            int grow = row0 + rr_[u];
            if (grow < n) {
                xp[u] = __builtin_nontemporal_load((const fv4*)(x + (size_t)grow * FIN + kc + kk_[u]));
            } else {
                xp[u] = (fv4){0.f, 0.f, 0.f, 0.f};
            }
        }
        wp[0] = w1[kc * HID + t];
        wp[1] = w1[kc * HID + t + 256];
    };

    prefetch(0);
    for (int kc = 0; kc < FIN; kc += KC) {
        __syncthreads();
#pragma unroll
        for (int u = 0; u < 2; ++u) {
            xs[kk_[u] + 0][rr_[u]] = xp[u].x;
            xs[kk_[u] + 1][rr_[u]] = xp[u].y;
            xs[kk_[u] + 2][rr_[u]] = xp[u].z;
            xs[kk_[u] + 3][rr_[u]] = xp[u].w;
        }
        wsc[t] = wp[0];
        wsc[t + 256] = wp[1];
        __syncthreads();
        if (kc + KC < FIN) prefetch(kc + KC);
#pragma unroll 8
        for (int k = 0; k < KC; ++k) {
            float xv = xs[k][rp];
            float4 wv = *(const float4*)&wsc[k * HID + cq];
            acc[0] = fmaf(xv, wv.x, acc[0]);
            acc[1] = fmaf(xv, wv.y, acc[1]);
            acc[2] = fmaf(xv, wv.z, acc[2]);
            acc[3] = fmaf(xv, wv.w, acc[3]);
        }
    }
    int r0 = row0 + rp;
    if (r0 < n) {
        float dv = dinv[r0];
        __half2* hp = (__half2*)(h1h + (size_t)r0 * HID + cq);
        hp[0] = __floats2half2_rn(dv * (acc[0] + bl[cq + 0]), dv * (acc[1] + bl[cq + 1]));
        hp[1] = __floats2half2_rn(dv * (acc[2] + bl[cq + 2]), dv * (acc[3] + bl[cq + 3]));
    }
}

// ---------------- agg1: 32 threads/node = 8 edge-strides x 4 lanes x 8B ----------
// R8: was 4 strides x 8 lanes x 4B. 8B/lane doubles edges-in-flight per wave (16 vs 8)
// and halves per-edge instruction count -- attacks gather latency, the aggs' cost.
// S = h1s[t] + sum_e h1s[src];  rowsum[t] = dinv_t*(dinv_t + sum_e dinv[src])

__global__ void agg1_kernel(const __half* __restrict__ in, const int* __restrict__ edges,
                            const int* __restrict__ row_ptr, const float* __restrict__ dinv,
                            __half* __restrict__ out16, float* __restrict__ rowsum, int n) {
    int gid = blockIdx.x * blockDim.x + threadIdx.x;
    int node = gid >> 5;
    int sub = (gid >> 2) & 7;   // 8 edge strides
    int c4 = gid & 3;           // 4 channel-quads (4 halves = 8B each)
    if (node >= n) return;
    const float2* tab = (const float2*)in;   // element = 4 halves
    float dv = dinv[node];
    float a0 = 0.f, a1 = 0.f, a2 = 0.f, a3 = 0.f, rs = 0.f;
    if (sub == 0) {
        float2 raw = tab[(size_t)node * 4 + c4];
        float2 lo = __half22float2(*(const __half2*)&raw.x);
        float2 hi = __half22float2(*(const __half2*)&raw.y);
        a0 = lo.x; a1 = lo.y; a2 = hi.x; a3 = hi.y; rs = dv;   // self (pre-scaled)
    }
    int beg = row_ptr[node], end = row_ptr[node + 1];
#pragma unroll 4
    for (int i = beg + sub; i < end; i += 8) {
        int src = edges[i];                         // 4 lanes same addr (broadcast)
        float2 raw = tab[(size_t)src * 4 + c4];     // 4 lanes x 8B = 32B contiguous
        float2 lo = __half22float2(*(const __half2*)&raw.x);
        float2 hi = __half22float2(*(const __half2*)&raw.y);
        a0 += lo.x; a1 += lo.y; a2 += hi.x; a3 += hi.y;
        rs += dinv[src];                            // same addr for 4 lanes (broadcast)
    }
    a0 += __shfl_xor(a0, 4);  a1 += __shfl_xor(a1, 4);  a2 += __shfl_xor(a2, 4);  a3 += __shfl_xor(a3, 4);  rs += __shfl_xor(rs, 4);
    a0 += __shfl_xor(a0, 8);  a1 += __shfl_xor(a1, 8);  a2 += __shfl_xor(a2, 8);  a3 += __shfl_xor(a3, 8);  rs += __shfl_xor(rs, 8);
    a0 += __shfl_xor(a0, 16); a1 += __shfl_xor(a1, 16); a2 += __shfl_xor(a2, 16); a3 += __shfl_xor(a3, 16); rs += __shfl_xor(rs, 16);
    if (sub == 0) {
        float dv2 = dv * dv;
        a0 = fmaxf(dv2 * a0, 0.f);           // dinv*relu(dinv*S) == relu(dinv^2*S)
        a1 = fmaxf(dv2 * a1, 0.f);
        a2 = fmaxf(dv2 * a2, 0.f);
        a3 = fmaxf(dv2 * a3, 0.f);
        float2 st;
        *(__half2*)&st.x = __floats2half2_rn(a0, a1);
        *(__half2*)&st.y = __floats2half2_rn(a2, a3);
        ((float2*)out16)[(size_t)node * 4 + c4] = st;
        if (c4 == 0) rowsum[node] = dv * rs;
    }
}

// ---------------- agg2 + final fused: out = log_softmax(dinv_t*S2 @ W2 + rowsum*b2) ---
// Same 8x4x8B mapping; epilogue (40-ch linear + log_softmax) on 2 threads/node.

__global__ void agg2_kernel(const __half* __restrict__ in, const int* __restrict__ edges,
                            const int* __restrict__ row_ptr, const float* __restrict__ dinv,
                            const float* __restrict__ rowsum,
                            const float* __restrict__ w2, const float* __restrict__ b2,
                            float* __restrict__ out, int n) {
    __shared__ float g2[8][HID + 1];
    __shared__ float wl[HID * NCLS];
    __shared__ float bl[NCLS];
    int t = threadIdx.x;
    for (int i = t; i < HID * NCLS; i += 256) wl[i] = w2[i];
    if (t < NCLS) bl[t] = b2[t];
    int gid = blockIdx.x * 256 + t;
    int node = gid >> 5;
    int sub = (gid >> 2) & 7;
    int c4 = gid & 3;
    int nl = t >> 5;
    float a0 = 0.f, a1 = 0.f, a2 = 0.f, a3 = 0.f;
    float dv = 0.f;
    if (node < n) {
        const float2* tab = (const float2*)in;
        dv = dinv[node];
        if (sub == 0) {
            float2 raw = tab[(size_t)node * 4 + c4];
            float2 lo = __half22float2(*(const __half2*)&raw.x);
            float2 hi = __half22float2(*(const __half2*)&raw.y);
            a0 = lo.x; a1 = lo.y; a2 = hi.x; a3 = hi.y;      // self (pre-scaled)
        }
        int beg = row_ptr[node], end = row_ptr[node + 1];
#pragma unroll 4
        for (int i = beg + sub; i < end; i += 8) {
            int src = edges[i];
            float2 raw = tab[(size_t)src * 4 + c4];
            float2 lo = __half22float2(*(const __half2*)&raw.x);
            float2 hi = __half22float2(*(const __half2*)&raw.y);
            a0 += lo.x; a1 += lo.y; a2 += hi.x; a3 += hi.y;
        }
    }
    a0 += __shfl_xor(a0, 4);  a1 += __shfl_xor(a1, 4);  a2 += __shfl_xor(a2, 4);  a3 += __shfl_xor(a3, 4);
    a0 += __shfl_xor(a0, 8);  a1 += __shfl_xor(a1, 8);  a2 += __shfl_xor(a2, 8);  a3 += __shfl_xor(a3, 8);
    a0 += __shfl_xor(a0, 16); a1 += __shfl_xor(a1, 16); a2 += __shfl_xor(a2, 16); a3 += __shfl_xor(a3, 16);
    if (sub == 0 && node < n) {
        g2[nl][c4 * 4 + 0] = dv * a0;
        g2[nl][c4 * 4 + 1] = dv * a1;
        g2[nl][c4 * 4 + 2] = dv * a2;
        g2[nl][c4 * 4 + 3] = dv * a3;
    }
    __syncthreads();
    if (t < 16) {
        int nl2 = t >> 1, half = t & 1;
        int node2 = blockIdx.x * 8 + nl2;
        float z[20];
        float m = -1e30f, se = 0.f;
        if (node2 < n) {
            float h[HID];
#pragma unroll
            for (int j = 0; j < HID; ++j) h[j] = g2[nl2][j];
            float rs = rowsum[node2];
            int c0 = half * 20;
#pragma unroll
            for (int c = 0; c < 20; ++c) {
                float s = rs * bl[c0 + c];
#pragma unroll
                for (int j = 0; j < HID; ++j) s = fmaf(h[j], wl[j * NCLS + c0 + c], s);
                z[c] = s;
            }
            m = z[0];
#pragma unroll
            for (int c = 1; c < 20; ++c) m = fmaxf(m, z[c]);
        }
        m = fmaxf(m, __shfl_xor(m, 1));
        if (node2 < n) {
#pragma unroll
            for (int c = 0; c < 20; ++c) se += __expf(z[c] - m);
        }
        se += __shfl_xor(se, 1);
        if (node2 < n) {
            float lse = m + __logf(se);
            float* orow = out + (size_t)node2 * NCLS + half * 20;
#pragma unroll
            for (int c = 0; c < 20; ++c) orow[c] = z[c] - lse;
        }
    }
}

// ---------------- launch ----------------

extern "C" void kernel_launch(void* const* d_in, const int* in_sizes, int n_in,
                              void* d_out, int out_size, void* d_ws, size_t ws_size,
                              hipStream_t stream) {
    const float* x  = (const float*)d_in[0];
    const int*   ei = (const int*)d_in[1];
    const float* w1 = (const float*)d_in[2];
    const float* b1 = (const float*)d_in[3];
    const float* w2 = (const float*)d_in[4];
    const float* b2 = (const float*)d_in[5];
    float* out = (float*)d_out;

    int N = in_sizes[0] / FIN;     // 100000
    int E = in_sizes[1] / 2;       // 3200000
    int nb = (N + 255) >> SHIFT;   // 391 coarse buckets (<= NBCAP)

    char* p = (char*)d_ws;
    auto alloc = [&](size_t bytes) -> char* {
        char* r = p;
        p += (bytes + 255) / 256 * 256;
        return r;
    };
    int*   gcur      = (int*)alloc((size_t)2 * NBCAP * 4);
    float* dinv      = (float*)alloc((size_t)N * 4);
    int*   row_ptr   = (int*)alloc((size_t)(N + 1) * 4);
    unsigned char* tmp_src = (unsigned char*)alloc((size_t)nb * CAP);      // 4.8 MB
    unsigned int*  tmp_tgt = (unsigned int*)alloc((size_t)nb * CAP * 4);   // 19.2 MB
    int*    edges    = (int*)alloc((size_t)E * 4);                         // 12.8 MB
    __half* h1h      = (__half*)alloc((size_t)N * HID * 2);                // 3.2 MB
    __half* gh       = (__half*)alloc((size_t)N * HID * 2);                // 3.2 MB
    float*  rowsum   = (float*)alloc((size_t)N * 4);

    zerocur_kernel<<<1, NBCAP, 0, stream>>>(gcur);
    fused_scatter_kernel<<<NBLK, 256, 0, stream>>>(ei, E, nb, gcur, tmp_src, tmp_tgt);
    fine_kernel<<<nb, 256, 0, stream>>>(tmp_src, tmp_tgt, gcur,
                                        dinv, row_ptr, edges, N, E, nb);
    linear1_kernel<<<(N + BR - 1) / BR, 256, 0, stream>>>(x, w1, b1, dinv, h1h, N);
    agg1_kernel<<<(N * 32 + 255) / 256, 256, 0, stream>>>(h1h, edges, row_ptr, dinv,
                                                          gh, rowsum, N);
    agg2_kernel<<<(N * 32 + 255) / 256, 256, 0, stream>>>(gh, edges, row_ptr, dinv,
                                                          rowsum, w2, b2, out, N);
}